// Round 15
// baseline (497.871 us; speedup 1.0000x reference)
//
#include <hip/hip_runtime.h>
#include <hip/hip_bf16.h>

#define NN 50000
#define EE 800000
#define ELN 100000
#define ETOT (EE + NN)
#define NT 311
#define SCAN_B ((NN + 255) / 256)   // 196

typedef _Float16 f16;
typedef f16 f16x8 __attribute__((ext_vector_type(8)));
typedef f16 f16x4 __attribute__((ext_vector_type(4)));
typedef f16 f16x2 __attribute__((ext_vector_type(2)));
typedef float f32x4 __attribute__((ext_vector_type(4)));

// ------- fused prep + layer-1 att scores: one wave per node -------
// lane owns channel `lane` of xc; computes xc row, writes once, dots with a1p.
__global__ __launch_bounds__(256) void k_prepatt(const float* __restrict__ x,
                                                 const float* __restrict__ emb,
                                                 const float* __restrict__ a1ps,
                                                 const float* __restrict__ a1pd,
                                                 f16* __restrict__ xc,
                                                 int* __restrict__ ntypes,
                                                 float* __restrict__ als,
                                                 float* __restrict__ ald)
{
    int gid = blockIdx.x * 256 + threadIdx.x;
    int n = gid >> 6, lane = gid & 63;
    if (n >= NN) return;
    int tpe = (int)x[(size_t)n * 33];
    tpe = tpe < 0 ? 0 : (tpe > NT - 1 ? NT - 1 : tpe);
    if (lane == 0) ntypes[n] = tpe;
    float v;
    if (lane < 16)      v = emb[tpe * 16 + lane];
    else if (lane < 48) v = x[(size_t)n * 33 + 1 + (lane - 16)];
    else                v = 0.f;
    f16 hv = (f16)v;
    xc[(size_t)n * 64 + lane] = hv;
    float xv = (float)hv;   // use the f16-rounded value, same as downstream
    float ps[4], pd[4];
    #pragma unroll
    for (int h = 0; h < 4; ++h) {
        ps[h] = xv * a1ps[h * 64 + lane];
        pd[h] = xv * a1pd[h * 64 + lane];
    }
    #pragma unroll
    for (int off = 32; off > 0; off >>= 1) {
        #pragma unroll
        for (int h = 0; h < 4; ++h) {
            ps[h] += __shfl_xor(ps[h], off, 64);
            pd[h] += __shfl_xor(pd[h], off, 64);
        }
    }
    if (lane == 0) {
        #pragma unroll
        for (int h = 0; h < 4; ++h) {
            als[n * 4 + h] = ps[h];
            ald[n * 4 + h] = pd[h];
        }
    }
}

// ---------------- weight convert+transpose: W[K][CN] f32 -> Wt[CN][KP] f16 ----------------
template<int K, int KP, int CN>
__global__ __launch_bounds__(256) void k_cvtw(const float* __restrict__ W,
                                              f16* __restrict__ Wt)
{
    int idx = blockIdx.x * 256 + threadIdx.x;
    if (idx >= CN * KP) return;
    int c = idx / KP;
    int k = idx - c * KP;
    Wt[idx] = (k < K) ? (f16)W[(size_t)k * CN + c] : (f16)0.f;
}

// ---- W1 per-head transpose ----
__global__ __launch_bounds__(256) void k_cvtw1(const float* __restrict__ W1,
                                               f16* __restrict__ Wt1)
{
    int idx = blockIdx.x * 256 + threadIdx.x;
    if (idx >= 4 * 64 * 64) return;
    int h = idx >> 12;
    int c = (idx >> 6) & 63;
    int k = idx & 63;
    Wt1[idx] = (k < 48) ? (f16)W1[(size_t)k * 256 + h * 64 + c] : (f16)0.f;
}

// ---- Wl1 transpose to f16: Wtl[c][k] = Wl1[k][c] ----
__global__ __launch_bounds__(256) void k_cvtwl(const float* __restrict__ Wl1,
                                               f16* __restrict__ Wtl)
{
    int idx = blockIdx.x * 256 + threadIdx.x;
    if (idx >= 64 * 256) return;
    int c = idx >> 8, k = idx & 255;
    Wtl[idx] = (f16)Wl1[(size_t)k * 64 + c];
}

// ---- fold a_src/a_dst through W1 ----
__global__ __launch_bounds__(256) void k_pre1(const float* __restrict__ W1,
                                              const float* __restrict__ as1,
                                              const float* __restrict__ ad1,
                                              float* __restrict__ a1ps,
                                              float* __restrict__ a1pd)
{
    int t = threadIdx.x;
    int h = t >> 6, k = t & 63;
    float ss = 0.f, sd = 0.f;
    if (k < 48) {
        for (int d = 0; d < 64; ++d) {
            float w = W1[(size_t)k * 256 + h * 64 + d];
            ss += w * as1[h * 64 + d];
            sd += w * ad1[h * 64 + d];
        }
    }
    a1ps[t] = ss;
    a1pd[t] = sd;
}

// ---------------- CSR build ----------------
__global__ __launch_bounds__(256) void k_deg(const int* __restrict__ ei,
                                             int* __restrict__ counts)
{
    int e = blockIdx.x * 256 + threadIdx.x;
    if (e >= ETOT) return;
    int dst = (e < EE) ? ei[EE + e] : (e - EE);
    atomicAdd(&counts[dst], 1);
}

// ---- 3-phase scan (phase 3 also fills dstarr) ----
__global__ __launch_bounds__(256) void k_scan1(const int* __restrict__ counts,
                                               int* __restrict__ rowptr,
                                               int* __restrict__ blocksums)
{
    __shared__ int s[256];
    int t = threadIdx.x;
    int i = blockIdx.x * 256 + t;
    int v = (i < NN) ? counts[i] : 0;
    s[t] = v;
    __syncthreads();
    #pragma unroll
    for (int off = 1; off < 256; off <<= 1) {
        int u = (t >= off) ? s[t - off] : 0;
        __syncthreads();
        s[t] += u;
        __syncthreads();
    }
    int incl = s[t];
    if (i < NN) rowptr[i] = incl - v;
    if (t == 255) blocksums[blockIdx.x] = incl;
}

__global__ __launch_bounds__(256) void k_scan2(int* __restrict__ blocksums,
                                               int* __restrict__ blockoff)
{
    __shared__ int s[256];
    int t = threadIdx.x;
    int v = (t < SCAN_B) ? blocksums[t] : 0;
    s[t] = v;
    __syncthreads();
    #pragma unroll
    for (int off = 1; off < 256; off <<= 1) {
        int u = (t >= off) ? s[t - off] : 0;
        __syncthreads();
        s[t] += u;
        __syncthreads();
    }
    if (t < SCAN_B) blockoff[t] = s[t] - v;
    if (t == SCAN_B - 1) blockoff[SCAN_B] = s[t];
}

__global__ __launch_bounds__(256) void k_scan3(int* __restrict__ rowptr,
                                               const int* __restrict__ blockoff,
                                               const int* __restrict__ counts,
                                               int* __restrict__ cursor,
                                               int* __restrict__ dstarr)
{
    int i = blockIdx.x * 256 + threadIdx.x;
    if (i < NN) {
        int v = rowptr[i] + blockoff[blockIdx.x];
        rowptr[i] = v;
        cursor[i] = v;
        int c = counts[i];
        for (int j = 0; j < c; ++j) dstarr[v + j] = i;
    }
    if (i == 0) rowptr[NN] = blockoff[SCAN_B];
}

__global__ __launch_bounds__(256) void k_fill(const int* __restrict__ ei,
                                              int* __restrict__ cursor,
                                              int* __restrict__ csr_src)
{
    int e = blockIdx.x * 256 + threadIdx.x;
    if (e >= ETOT) return;
    int src, dst;
    if (e < EE) { src = ei[e]; dst = ei[EE + e]; }
    else        { src = e - EE; dst = e - EE; }
    int pos = atomicAdd(&cursor[dst], 1);
    csr_src[pos] = src;
}

// ------------- MFMA f16 GEMM, optional fused attention-score partials -------------
template<int K, int CN, int H>
__global__ __launch_bounds__(256) void k_gemmh(const f16* __restrict__ A,
                                               const f16* __restrict__ Wt,
                                               f16* __restrict__ O,
                                               int nrows,
                                               const float* __restrict__ asrc,
                                               const float* __restrict__ adst,
                                               float* __restrict__ als,
                                               float* __restrict__ ald)
{
    constexpr int LDA = 40;
    __shared__ f16 As[64 * LDA];
    __shared__ f16 Bs[64 * LDA];
    const int t = threadIdx.x;
    const int w = t >> 6;
    const int lane = t & 63;
    const int m = lane & 15;
    const int quad = lane >> 4;
    const int row0 = blockIdx.x * 64;
    const int col0 = blockIdx.y * 64;
    const int r_st = t >> 2;
    const int seg  = (t & 3) * 8;
    f32x4 acc[4] = {{0.f,0.f,0.f,0.f},{0.f,0.f,0.f,0.f},{0.f,0.f,0.f,0.f},{0.f,0.f,0.f,0.f}};
    for (int k0 = 0; k0 < K; k0 += 32) {
        int gr = row0 + r_st;
        f16x8 av = {0,0,0,0,0,0,0,0};
        if (gr < nrows) av = *(const f16x8*)&A[(size_t)gr * K + k0 + seg];
        *(f16x8*)&As[r_st * LDA + seg] = av;
        f16x8 bv = *(const f16x8*)&Wt[(size_t)(col0 + r_st) * K + k0 + seg];
        *(f16x8*)&Bs[r_st * LDA + seg] = bv;
        __syncthreads();
        f16x8 af = *(const f16x8*)&As[(w * 16 + m) * LDA + quad * 8];
        #pragma unroll
        for (int g = 0; g < 4; ++g) {
            f16x8 bf = *(const f16x8*)&Bs[(g * 16 + m) * LDA + quad * 8];
            acc[g] = __builtin_amdgcn_mfma_f32_16x16x32_f16(af, bf, acc[g], 0, 0, 0);
        }
        __syncthreads();
    }
    #pragma unroll
    for (int g = 0; g < 4; ++g) {
        #pragma unroll
        for (int reg = 0; reg < 4; ++reg) {
            int gr = row0 + w * 16 + quad * 4 + reg;
            int gc = col0 + g * 16 + m;
            if (gr < nrows) O[(size_t)gr * CN + gc] = (f16)acc[g][reg];
        }
    }
    if constexpr (H > 0) {
        constexpr int D = CN / H;
        const int head = col0 / D;
        float ps[4] = {}, pd[4] = {};
        #pragma unroll
        for (int g = 0; g < 4; ++g) {
            int col = col0 + g * 16 + m;
            float a_s = asrc[col], a_d = adst[col];
            #pragma unroll
            for (int reg = 0; reg < 4; ++reg) {
                ps[reg] += acc[g][reg] * a_s;
                pd[reg] += acc[g][reg] * a_d;
            }
        }
        #pragma unroll
        for (int off = 1; off < 16; off <<= 1) {
            #pragma unroll
            for (int reg = 0; reg < 4; ++reg) {
                ps[reg] += __shfl_xor(ps[reg], off, 64);
                pd[reg] += __shfl_xor(pd[reg], off, 64);
            }
        }
        if (m == 0) {
            #pragma unroll
            for (int reg = 0; reg < 4; ++reg) {
                int gr = row0 + w * 16 + quad * 4 + reg;
                if (gr < nrows) {
                    atomicAdd(&als[gr * H + head], ps[reg]);
                    atomicAdd(&ald[gr * H + head], pd[reg]);
                }
            }
        }
    }
}

// ----- layer-1 per-head GEMM with fused bias+ELU -----
__global__ __launch_bounds__(256) void k_gemm1h(const f16* __restrict__ A,
                                                const f16* __restrict__ Wt1,
                                                const float* __restrict__ bias,
                                                f16* __restrict__ O,
                                                int nrows)
{
    constexpr int LDA = 40;
    __shared__ f16 As[64 * LDA];
    __shared__ f16 Bs[64 * LDA];
    const int t = threadIdx.x;
    const int w = t >> 6;
    const int lane = t & 63;
    const int m = lane & 15;
    const int quad = lane >> 4;
    const int row0 = blockIdx.x * 64;
    const int head = blockIdx.y;
    const int r_st = t >> 2;
    const int seg  = (t & 3) * 8;
    f32x4 acc[4] = {{0.f,0.f,0.f,0.f},{0.f,0.f,0.f,0.f},{0.f,0.f,0.f,0.f},{0.f,0.f,0.f,0.f}};
    for (int k0 = 0; k0 < 64; k0 += 32) {
        int gr = row0 + r_st;
        f16x8 av = {0,0,0,0,0,0,0,0};
        if (gr < nrows) av = *(const f16x8*)&A[(size_t)gr * 256 + head * 64 + k0 + seg];
        *(f16x8*)&As[r_st * LDA + seg] = av;
        f16x8 bv = *(const f16x8*)&Wt1[(size_t)head * 4096 + (size_t)r_st * 64 + k0 + seg];
        *(f16x8*)&Bs[r_st * LDA + seg] = bv;
        __syncthreads();
        f16x8 af = *(const f16x8*)&As[(w * 16 + m) * LDA + quad * 8];
        #pragma unroll
        for (int g = 0; g < 4; ++g) {
            f16x8 bf = *(const f16x8*)&Bs[(g * 16 + m) * LDA + quad * 8];
            acc[g] = __builtin_amdgcn_mfma_f32_16x16x32_f16(af, bf, acc[g], 0, 0, 0);
        }
        __syncthreads();
    }
    #pragma unroll
    for (int g = 0; g < 4; ++g) {
        #pragma unroll
        for (int reg = 0; reg < 4; ++reg) {
            int gr = row0 + w * 16 + quad * 4 + reg;
            int col = head * 64 + g * 16 + m;
            if (gr < nrows) {
                float v = acc[g][reg] + bias[col];
                v = v > 0.f ? v : (__expf(v) - 1.f);
                O[(size_t)gr * 256 + col] = (f16)v;
            }
        }
    }
}

// -------- per-edge exp weights --------
template<int H>
__global__ __launch_bounds__(256) void k_ew(const int* __restrict__ csr,
                                            const int* __restrict__ dstarr,
                                            const float* __restrict__ als,
                                            const float* __restrict__ ald,
                                            float* __restrict__ earr)
{
    int i = blockIdx.x * 256 + threadIdx.x;
    if (i >= ETOT) return;
    int s = csr[i], d = dstarr[i];
    #pragma unroll
    for (int hh = 0; hh < H; ++hh) {
        float l = als[s * H + hh] + ald[d * H + hh];
        l = l > 0.f ? l : 0.2f * l;
        earr[(size_t)i * H + hh] = __expf(fminf(l, 80.f));
    }
}

// ------- layer-1 aggregate over xc: 2 parities, f16x2 loads, 4-edge unroll -------
__global__ __launch_bounds__(256) void k_aggx(const int* __restrict__ rowptr,
                                              const int* __restrict__ csr,
                                              const float* __restrict__ earr, // [i][4]
                                              const f16* __restrict__ xc,
                                              f16* __restrict__ xagg)
{
    int gid = blockIdx.x * 256 + threadIdx.x;
    int n = gid >> 6, lane = gid & 63;
    if (n >= NN) return;
    int p  = lane >> 5;          // parity 0/1
    int cb = (lane & 31) * 2;    // channel base 0..62
    int r0 = rowptr[n], r1 = rowptr[n + 1];
    float a0[2] = {}, a1[2] = {}, a2[2] = {}, a3[2] = {};
    float d0 = 0.f, d1 = 0.f, d2 = 0.f, d3 = 0.f;
    int i = r0;
    for (; i + 4 <= r1; i += 4) {
        int i0 = i + p, i1 = i + 2 + p;
        int s0 = csr[i0], s1 = csr[i1];
        float4 e0 = *(const float4*)&earr[(size_t)i0 * 4];
        float4 e1 = *(const float4*)&earr[(size_t)i1 * 4];
        f16x2 x0 = *(const f16x2*)&xc[(size_t)s0 * 64 + cb];
        f16x2 x1 = *(const f16x2*)&xc[(size_t)s1 * 64 + cb];
        #pragma unroll
        for (int j = 0; j < 2; ++j) {
            float v0 = (float)x0[j], v1 = (float)x1[j];
            a0[j] += e0.x * v0 + e1.x * v1;
            a1[j] += e0.y * v0 + e1.y * v1;
            a2[j] += e0.z * v0 + e1.z * v1;
            a3[j] += e0.w * v0 + e1.w * v1;
        }
        d0 += e0.x + e1.x; d1 += e0.y + e1.y;
        d2 += e0.z + e1.z; d3 += e0.w + e1.w;
    }
    for (; i < r1; i += 2) {
        int ii = i + p;
        bool v = ii < r1;
        int s0 = csr[v ? ii : r0];
        float4 e0 = *(const float4*)&earr[(size_t)(v ? ii : r0) * 4];
        if (!v) { e0.x = 0.f; e0.y = 0.f; e0.z = 0.f; e0.w = 0.f; }
        f16x2 x0 = *(const f16x2*)&xc[(size_t)s0 * 64 + cb];
        #pragma unroll
        for (int j = 0; j < 2; ++j) {
            float v0 = (float)x0[j];
            a0[j] += e0.x * v0; a1[j] += e0.y * v0;
            a2[j] += e0.z * v0; a3[j] += e0.w * v0;
        }
        d0 += e0.x; d1 += e0.y; d2 += e0.z; d3 += e0.w;
    }
    #pragma unroll
    for (int j = 0; j < 2; ++j) {
        a0[j] += __shfl_xor(a0[j], 32, 64);
        a1[j] += __shfl_xor(a1[j], 32, 64);
        a2[j] += __shfl_xor(a2[j], 32, 64);
        a3[j] += __shfl_xor(a3[j], 32, 64);
    }
    d0 += __shfl_xor(d0, 32, 64);
    d1 += __shfl_xor(d1, 32, 64);
    d2 += __shfl_xor(d2, 32, 64);
    d3 += __shfl_xor(d3, 32, 64);
    if (p == 0) {
        float i0 = 1.f / d0, i1 = 1.f / d1, i2 = 1.f / d2, i3 = 1.f / d3;
        size_t base = (size_t)n * 256 + cb;
        f16x2 o0 = {(f16)(a0[0] * i0), (f16)(a0[1] * i0)};
        f16x2 o1 = {(f16)(a1[0] * i1), (f16)(a1[1] * i1)};
        f16x2 o2 = {(f16)(a2[0] * i2), (f16)(a2[1] * i2)};
        f16x2 o3 = {(f16)(a3[0] * i3), (f16)(a3[1] * i3)};
        *(f16x2*)&xagg[base]       = o0;
        *(f16x2*)&xagg[base + 64]  = o1;
        *(f16x2*)&xagg[base + 128] = o2;
        *(f16x2*)&xagg[base + 192] = o3;
    }
}

// ------- layer-2 aggregate: 32 lanes/row (f16x8), 2 edge-parities, 4x unroll -------
__global__ __launch_bounds__(256) void k_agg2f(const int* __restrict__ rowptr,
                                               const int* __restrict__ csr,
                                               const float* __restrict__ earr, // [i][2]
                                               const f16* __restrict__ h,
                                               const float* __restrict__ bias,
                                               f16* __restrict__ z)
{
    int gid = blockIdx.x * 256 + threadIdx.x;
    int n = gid >> 6, lane = gid & 63;
    if (n >= NN) return;
    int p  = lane >> 5;          // edge parity 0/1
    int cb = (lane & 31) * 8;    // channel base 0..248
    int head = cb >> 7;
    int r0 = rowptr[n], r1 = rowptr[n + 1];
    float a[8] = {};
    float den = 0.f;
    int i = r0;
    for (; i + 8 <= r1; i += 8) {
        int i0 = i + p, i1 = i + 2 + p, i2 = i + 4 + p, i3 = i + 6 + p;
        int s0 = csr[i0], s1 = csr[i1], s2 = csr[i2], s3 = csr[i3];
        float e0 = earr[(size_t)i0 * 2 + head];
        float e1 = earr[(size_t)i1 * 2 + head];
        float e2 = earr[(size_t)i2 * 2 + head];
        float e3 = earr[(size_t)i3 * 2 + head];
        f16x8 h0 = *(const f16x8*)&h[(size_t)s0 * 256 + cb];
        f16x8 h1 = *(const f16x8*)&h[(size_t)s1 * 256 + cb];
        f16x8 h2 = *(const f16x8*)&h[(size_t)s2 * 256 + cb];
        f16x8 h3 = *(const f16x8*)&h[(size_t)s3 * 256 + cb];
        #pragma unroll
        for (int j = 0; j < 8; ++j)
            a[j] += e0 * (float)h0[j] + e1 * (float)h1[j]
                  + e2 * (float)h2[j] + e3 * (float)h3[j];
        den += e0 + e1 + e2 + e3;
    }
    for (; i < r1; i += 2) {
        int ii = i + p;
        bool v = ii < r1;
        int s0 = csr[v ? ii : r0];
        float e0 = v ? earr[(size_t)ii * 2 + head] : 0.f;
        f16x8 h0 = *(const f16x8*)&h[(size_t)s0 * 256 + cb];
        #pragma unroll
        for (int j = 0; j < 8; ++j) a[j] += e0 * (float)h0[j];
        den += e0;
    }
    #pragma unroll
    for (int j = 0; j < 8; ++j) a[j] += __shfl_xor(a[j], 32, 64);
    den += __shfl_xor(den, 32, 64);
    if (p == 0) {
        float inv = 1.f / den;
        f16x8 o;
        #pragma unroll
        for (int j = 0; j < 8; ++j) {
            float v = a[j] * inv + bias[cb + j];
            v = v > 0.f ? v : (__expf(v) - 1.f);
            o[j] = (f16)v;
        }
        *(f16x8*)&z[(size_t)n * 256 + cb] = o;
    }
}

// ------- layer-3 aggregate: 16 lanes/row (f16x8), 4 edge-parities, 2x unroll -------
__global__ __launch_bounds__(256) void k_agg3(const int* __restrict__ rowptr,
                                              const int* __restrict__ csr,
                                              const float* __restrict__ earr, // [i]
                                              const f16* __restrict__ h,
                                              const float* __restrict__ bias,
                                              f16* __restrict__ z)
{
    int gid = blockIdx.x * 256 + threadIdx.x;
    int n = gid >> 6, lane = gid & 63;
    if (n >= NN) return;
    int p  = lane >> 4;          // edge parity 0..3
    int cb = (lane & 15) * 8;    // channel base 0..120
    int r0 = rowptr[n], r1 = rowptr[n + 1];
    float a[8] = {};
    float den = 0.f;
    int i = r0;
    for (; i + 8 <= r1; i += 8) {
        int i0 = i + p, i1 = i + 4 + p;
        int s0 = csr[i0], s1 = csr[i1];
        float e0 = earr[i0], e1 = earr[i1];
        f16x8 h0 = *(const f16x8*)&h[(size_t)s0 * 128 + cb];
        f16x8 h1 = *(const f16x8*)&h[(size_t)s1 * 128 + cb];
        #pragma unroll
        for (int j = 0; j < 8; ++j)
            a[j] += e0 * (float)h0[j] + e1 * (float)h1[j];
        den += e0 + e1;
    }
    for (; i < r1; i += 4) {
        int ii = i + p;
        bool v = ii < r1;
        int s0 = csr[v ? ii : r0];
        float e0 = v ? earr[ii] : 0.f;
        f16x8 h0 = *(const f16x8*)&h[(size_t)s0 * 128 + cb];
        #pragma unroll
        for (int j = 0; j < 8; ++j) a[j] += e0 * (float)h0[j];
        den += e0;
    }
    #pragma unroll
    for (int j = 0; j < 8; ++j) {
        a[j] += __shfl_xor(a[j], 16, 64);
        a[j] += __shfl_xor(a[j], 32, 64);
    }
    den += __shfl_xor(den, 16, 64);
    den += __shfl_xor(den, 32, 64);
    if (lane < 16) {
        float inv = 1.f / den;
        f16x8 o;
        #pragma unroll
        for (int j = 0; j < 8; ++j)
            o[j] = (f16)(a[j] * inv + bias[cb + j]);
        *(f16x8*)&z[(size_t)n * 128 + cb] = o;
    }
}

// ---------- MFMA decoder: 64 edges/block, ef[64][256]f16 @ Wtl[64][256]^T ----------
#define DLDA 264
__global__ __launch_bounds__(256) void k_decm(const f16* __restrict__ z3,
                                              const int* __restrict__ eli,
                                              const int* __restrict__ ntypes,
                                              const f16* __restrict__ Wtl,  // [64][256]
                                              const float* __restrict__ bl1,
                                              const float* __restrict__ Wl2,
                                              const float* __restrict__ bl2,
                                              const float* __restrict__ tb,
                                              float* __restrict__ out)
{
    __shared__ f16 As[64 * DLDA];
    __shared__ int sls[64], sld[64];
    const int t = threadIdx.x;
    const int e0 = blockIdx.x * 64;
    if (t < 64) {
        int e = e0 + t;
        sls[t] = (e < ELN) ? eli[e] : 0;
        sld[t] = (e < ELN) ? eli[ELN + e] : 0;
    }
    __syncthreads();
    {
        int r = t & 63;
        int seg = t >> 6;
        int base = seg * 64;
        int node = (base < 128) ? sls[r] : sld[r];
        int zoff = base & 127;
        #pragma unroll
        for (int j = 0; j < 8; ++j) {
            f16x8 v = *(const f16x8*)&z3[(size_t)node * 128 + zoff + j * 8];
            *(f16x8*)&As[r * DLDA + base + j * 8] = v;
        }
    }
    __syncthreads();
    const int w = t >> 6;
    const int lane = t & 63;
    const int m = lane & 15;
    const int quad = lane >> 4;
    f32x4 acc[4] = {{0.f,0.f,0.f,0.f},{0.f,0.f,0.f,0.f},{0.f,0.f,0.f,0.f},{0.f,0.f,0.f,0.f}};
    for (int k0 = 0; k0 < 256; k0 += 32) {
        f16x8 af = *(const f16x8*)&As[(w * 16 + m) * DLDA + k0 + quad * 8];
        #pragma unroll
        for (int g = 0; g < 4; ++g) {
            f16x8 bf = *(const f16x8*)&Wtl[(size_t)(g * 16 + m) * 256 + k0 + quad * 8];
            acc[g] = __builtin_amdgcn_mfma_f32_16x16x32_f16(af, bf, acc[g], 0, 0, 0);
        }
    }
    float s[4] = {0.f, 0.f, 0.f, 0.f};
    #pragma unroll
    for (int g = 0; g < 4; ++g) {
        int col = g * 16 + m;
        float b = bl1[col], wv = Wl2[col];
        #pragma unroll
        for (int reg = 0; reg < 4; ++reg) {
            float hv = fmaxf(acc[g][reg] + b, 0.f);
            s[reg] += hv * wv;
        }
    }
    #pragma unroll
    for (int off = 1; off < 16; off <<= 1) {
        #pragma unroll
        for (int reg = 0; reg < 4; ++reg) s[reg] += __shfl_xor(s[reg], off, 64);
    }
    if (m == 0) {
        float b2v = bl2[0];
        #pragma unroll
        for (int reg = 0; reg < 4; ++reg) {
            int r = w * 16 + quad * 4 + reg;
            int e = e0 + r;
            if (e < ELN) {
                out[e] = s[reg] + b2v +
                         tb[(size_t)ntypes[sls[r]] * NT + ntypes[sld[r]]];
            }
        }
    }
}

// ---------------- launch ----------------
extern "C" void kernel_launch(void* const* d_in, const int* in_sizes, int n_in,
                              void* d_out, int out_size, void* d_ws, size_t ws_size,
                              hipStream_t stream)
{
    const float* x   = (const float*)d_in[0];
    const int*   ei  = (const int*)d_in[1];
    const int*   eli = (const int*)d_in[2];
    const float* emb = (const float*)d_in[3];
    const float* W1  = (const float*)d_in[4];
    const float* as1 = (const float*)d_in[5];
    const float* ad1 = (const float*)d_in[6];
    const float* b1  = (const float*)d_in[7];
    const float* W2  = (const float*)d_in[8];
    const float* as2 = (const float*)d_in[9];
    const float* ad2 = (const float*)d_in[10];
    const float* b2  = (const float*)d_in[11];
    const float* W3  = (const float*)d_in[12];
    const float* as3 = (const float*)d_in[13];
    const float* ad3 = (const float*)d_in[14];
    const float* b3  = (const float*)d_in[15];
    const float* Wl1 = (const float*)d_in[16];
    const float* bl1 = (const float*)d_in[17];
    const float* Wl2 = (const float*)d_in[18];
    const float* bl2 = (const float*)d_in[19];
    const float* tb  = (const float*)d_in[20];
    float* out = (float*)d_out;

    char* ws = (char*)d_ws;
    size_t off = 0;
    auto alloc = [&](size_t bytes) { size_t o = off; off = (off + bytes + 255) & ~(size_t)255; return o; };
    int*   ntypes = (int*)  (ws + alloc((size_t)NN * 4));
    f16*   xc16   = (f16*)  (ws + alloc((size_t)NN * 64 * 2));
    int*   counts = (int*)  (ws + alloc((size_t)NN * 4));
    int*   cursor = (int*)  (ws + alloc((size_t)NN * 4));
    int*   rowptr = (int*)  (ws + alloc((size_t)(NN + 1) * 4));
    int*   csr    = (int*)  (ws + alloc((size_t)ETOT * 4));
    int*   dstarr = (int*)  (ws + alloc((size_t)ETOT * 4));
    int*   bsums  = (int*)  (ws + alloc((size_t)(SCAN_B + 1) * 4));
    int*   boff   = (int*)  (ws + alloc((size_t)(SCAN_B + 1) * 4));
    float* als    = (float*)(ws + alloc((size_t)NN * 4 * 4));
    float* ald    = (float*)(ws + alloc((size_t)NN * 4 * 4));
    float* earr   = (float*)(ws + alloc((size_t)ETOT * 4 * 4));
    f16*   h16    = (f16*)  (ws + alloc((size_t)NN * 256 * 2));   // also xagg
    f16*   z16    = (f16*)  (ws + alloc((size_t)NN * 256 * 2));
    f16*   Wt1    = (f16*)  (ws + alloc((size_t)4 * 64 * 64 * 2));
    f16*   Wt2    = (f16*)  (ws + alloc((size_t)256 * 256 * 2));
    f16*   Wt3    = (f16*)  (ws + alloc((size_t)128 * 256 * 2));
    f16*   Wtl    = (f16*)  (ws + alloc((size_t)64 * 256 * 2));
    float* a1ps   = (float*)(ws + alloc(256 * 4));
    float* a1pd   = (float*)(ws + alloc(256 * 4));

    hipMemsetAsync(counts, 0, (size_t)NN * 4, stream);

    const int gN   = (NN + 255) / 256;
    const int gE   = (ETOT + 255) / 256;
    const int RB   = (NN + 63) / 64;       // 782
    const int gW1  = (NN + 3) / 4;         // 1 wave/node

    k_pre1<<<1, 256, 0, stream>>>(W1, as1, ad1, a1ps, a1pd);
    k_prepatt<<<gW1, 256, 0, stream>>>(x, emb, a1ps, a1pd, xc16, ntypes, als, ald);
    k_cvtw1<<<(4 * 64 * 64 + 255) / 256, 256, 0, stream>>>(W1, Wt1);
    k_cvtw<256, 256, 256><<<(256 * 256 + 255) / 256, 256, 0, stream>>>(W2, Wt2);
    k_cvtw<256, 256, 128><<<(128 * 256 + 255) / 256, 256, 0, stream>>>(W3, Wt3);
    k_cvtwl<<<(64 * 256 + 255) / 256, 256, 0, stream>>>(Wl1, Wtl);
    k_deg <<<gE, 256, 0, stream>>>(ei, counts);
    k_scan1<<<SCAN_B, 256, 0, stream>>>(counts, rowptr, bsums);
    k_scan2<<<1, 256, 0, stream>>>(bsums, boff);
    k_scan3<<<SCAN_B, 256, 0, stream>>>(rowptr, boff, counts, cursor, dstarr);
    k_fill<<<gE, 256, 0, stream>>>(ei, cursor, csr);

    // Layer 1 (linearity-swapped; scores already computed by k_prepatt)
    k_ew<4><<<gE, 256, 0, stream>>>(csr, dstarr, als, ald, earr);
    k_aggx<<<gW1, 256, 0, stream>>>(rowptr, csr, earr, xc16, h16 /*xagg*/);
    k_gemm1h<<<dim3(RB, 4), 256, 0, stream>>>(h16 /*xagg*/, Wt1, b1, z16, NN);

    // Layer 2 (att fused into GEMM epilogue)
    hipMemsetAsync(als, 0, (size_t)NN * 2 * 4, stream);
    hipMemsetAsync(ald, 0, (size_t)NN * 2 * 4, stream);
    k_gemmh<256, 256, 2><<<dim3(RB, 4), 256, 0, stream>>>(z16, Wt2, h16, NN, as2, ad2, als, ald);
    k_ew<2><<<gE, 256, 0, stream>>>(csr, dstarr, als, ald, earr);
    k_agg2f<<<gW1, 256, 0, stream>>>(rowptr, csr, earr, h16, b2, z16);

    // Layer 3 (att fused into GEMM epilogue)
    hipMemsetAsync(als, 0, (size_t)NN * 4, stream);
    hipMemsetAsync(ald, 0, (size_t)NN * 4, stream);
    k_gemmh<256, 128, 1><<<dim3(RB, 2), 256, 0, stream>>>(z16, Wt3, h16, NN, as3, ad3, als, ald);
    k_ew<1><<<gE, 256, 0, stream>>>(csr, dstarr, als, ald, earr);
    k_agg3<<<gW1, 256, 0, stream>>>(rowptr, csr, earr, h16, b3, z16);

    // Decoder (MFMA)
    k_decm<<<(ELN + 63) / 64, 256, 0, stream>>>(z16, eli, ntypes, Wtl, bl1, Wl2, bl2, tb, out);
}

// Round 16
// 487.781 us; speedup vs baseline: 1.0207x; 1.0207x over previous
//
#include <hip/hip_runtime.h>
#include <hip/hip_bf16.h>

#define NN 50000
#define EE 800000
#define ELN 100000
#define ETOT (EE + NN)
#define NT 311
#define SCAN_B ((NN + 255) / 256)   // 196

typedef _Float16 f16;
typedef f16 f16x8 __attribute__((ext_vector_type(8)));
typedef f16 f16x4 __attribute__((ext_vector_type(4)));
typedef f16 f16x2 __attribute__((ext_vector_type(2)));
typedef float f32x4 __attribute__((ext_vector_type(4)));

// ------- fused prep + layer-1 att scores: one wave per node -------
__global__ __launch_bounds__(256) void k_prepatt(const float* __restrict__ x,
                                                 const float* __restrict__ emb,
                                                 const float* __restrict__ a1ps,
                                                 const float* __restrict__ a1pd,
                                                 f16* __restrict__ xc,
                                                 int* __restrict__ ntypes,
                                                 float* __restrict__ als,
                                                 float* __restrict__ ald)
{
    int gid = blockIdx.x * 256 + threadIdx.x;
    int n = gid >> 6, lane = gid & 63;
    if (n >= NN) return;
    int tpe = (int)x[(size_t)n * 33];
    tpe = tpe < 0 ? 0 : (tpe > NT - 1 ? NT - 1 : tpe);
    if (lane == 0) ntypes[n] = tpe;
    float v;
    if (lane < 16)      v = emb[tpe * 16 + lane];
    else if (lane < 48) v = x[(size_t)n * 33 + 1 + (lane - 16)];
    else                v = 0.f;
    f16 hv = (f16)v;
    xc[(size_t)n * 64 + lane] = hv;
    float xv = (float)hv;
    float ps[4], pd[4];
    #pragma unroll
    for (int h = 0; h < 4; ++h) {
        ps[h] = xv * a1ps[h * 64 + lane];
        pd[h] = xv * a1pd[h * 64 + lane];
    }
    #pragma unroll
    for (int off = 32; off > 0; off >>= 1) {
        #pragma unroll
        for (int h = 0; h < 4; ++h) {
            ps[h] += __shfl_xor(ps[h], off, 64);
            pd[h] += __shfl_xor(pd[h], off, 64);
        }
    }
    if (lane == 0) {
        #pragma unroll
        for (int h = 0; h < 4; ++h) {
            als[n * 4 + h] = ps[h];
            ald[n * 4 + h] = pd[h];
        }
    }
}

// ---- all weight conversions in one kernel ----
// ranges: [0,16384) Wt1 | [16384,81920) Wt2 | [81920,114688) Wt3 | [114688,131072) Wtl
__global__ __launch_bounds__(256) void k_cvtall(const float* __restrict__ W1,
                                                const float* __restrict__ W2,
                                                const float* __restrict__ W3,
                                                const float* __restrict__ Wl1,
                                                f16* __restrict__ Wt1,
                                                f16* __restrict__ Wt2,
                                                f16* __restrict__ Wt3,
                                                f16* __restrict__ Wtl)
{
    int idx = blockIdx.x * 256 + threadIdx.x;
    if (idx < 16384) {
        int h = idx >> 12, c = (idx >> 6) & 63, k = idx & 63;
        Wt1[idx] = (k < 48) ? (f16)W1[(size_t)k * 256 + h * 64 + c] : (f16)0.f;
    } else if (idx < 81920) {
        int i = idx - 16384;
        int c = i >> 8, k = i & 255;
        Wt2[i] = (f16)W2[(size_t)k * 256 + c];
    } else if (idx < 114688) {
        int i = idx - 81920;
        int c = i >> 8, k = i & 255;
        Wt3[i] = (f16)W3[(size_t)k * 128 + c];
    } else if (idx < 131072) {
        int i = idx - 114688;
        int c = i >> 8, k = i & 255;
        Wtl[i] = (f16)Wl1[(size_t)k * 64 + c];
    }
}

// ---- fold a_src/a_dst through W1 ----
__global__ __launch_bounds__(256) void k_pre1(const float* __restrict__ W1,
                                              const float* __restrict__ as1,
                                              const float* __restrict__ ad1,
                                              float* __restrict__ a1ps,
                                              float* __restrict__ a1pd)
{
    int t = threadIdx.x;
    int h = t >> 6, k = t & 63;
    float ss = 0.f, sd = 0.f;
    if (k < 48) {
        for (int d = 0; d < 64; ++d) {
            float w = W1[(size_t)k * 256 + h * 64 + d];
            ss += w * as1[h * 64 + d];
            sd += w * ad1[h * 64 + d];
        }
    }
    a1ps[t] = ss;
    a1pd[t] = sd;
}

// ---------------- CSR build ----------------
__global__ __launch_bounds__(256) void k_deg(const int* __restrict__ ei,
                                             int* __restrict__ counts)
{
    int e = blockIdx.x * 256 + threadIdx.x;
    if (e >= ETOT) return;
    int dst = (e < EE) ? ei[EE + e] : (e - EE);
    atomicAdd(&counts[dst], 1);
}

__global__ __launch_bounds__(256) void k_scan1(const int* __restrict__ counts,
                                               int* __restrict__ rowptr,
                                               int* __restrict__ blocksums)
{
    __shared__ int s[256];
    int t = threadIdx.x;
    int i = blockIdx.x * 256 + t;
    int v = (i < NN) ? counts[i] : 0;
    s[t] = v;
    __syncthreads();
    #pragma unroll
    for (int off = 1; off < 256; off <<= 1) {
        int u = (t >= off) ? s[t - off] : 0;
        __syncthreads();
        s[t] += u;
        __syncthreads();
    }
    int incl = s[t];
    if (i < NN) rowptr[i] = incl - v;
    if (t == 255) blocksums[blockIdx.x] = incl;
}

__global__ __launch_bounds__(256) void k_scan2(int* __restrict__ blocksums,
                                               int* __restrict__ blockoff)
{
    __shared__ int s[256];
    int t = threadIdx.x;
    int v = (t < SCAN_B) ? blocksums[t] : 0;
    s[t] = v;
    __syncthreads();
    #pragma unroll
    for (int off = 1; off < 256; off <<= 1) {
        int u = (t >= off) ? s[t - off] : 0;
        __syncthreads();
        s[t] += u;
        __syncthreads();
    }
    if (t < SCAN_B) blockoff[t] = s[t] - v;
    if (t == SCAN_B - 1) blockoff[SCAN_B] = s[t];
}

__global__ __launch_bounds__(256) void k_scan3(int* __restrict__ rowptr,
                                               const int* __restrict__ blockoff,
                                               const int* __restrict__ counts,
                                               int* __restrict__ cursor,
                                               int* __restrict__ dstarr)
{
    int i = blockIdx.x * 256 + threadIdx.x;
    if (i < NN) {
        int v = rowptr[i] + blockoff[blockIdx.x];
        rowptr[i] = v;
        cursor[i] = v;
        int c = counts[i];
        for (int j = 0; j < c; ++j) dstarr[v + j] = i;
    }
    if (i == 0) rowptr[NN] = blockoff[SCAN_B];
}

__global__ __launch_bounds__(256) void k_fill(const int* __restrict__ ei,
                                              int* __restrict__ cursor,
                                              int* __restrict__ csr_src)
{
    int e = blockIdx.x * 256 + threadIdx.x;
    if (e >= ETOT) return;
    int src, dst;
    if (e < EE) { src = ei[e]; dst = ei[EE + e]; }
    else        { src = e - EE; dst = e - EE; }
    int pos = atomicAdd(&cursor[dst], 1);
    __builtin_nontemporal_store(src, &csr_src[pos]);
}

// ------------- MFMA f16 GEMM, optional fused attention-score partials -------------
template<int K, int CN, int H>
__global__ __launch_bounds__(256) void k_gemmh(const f16* __restrict__ A,
                                               const f16* __restrict__ Wt,
                                               f16* __restrict__ O,
                                               int nrows,
                                               const float* __restrict__ asrc,
                                               const float* __restrict__ adst,
                                               float* __restrict__ als,
                                               float* __restrict__ ald)
{
    constexpr int LDA = 40;
    __shared__ f16 As[64 * LDA];
    __shared__ f16 Bs[64 * LDA];
    const int t = threadIdx.x;
    const int w = t >> 6;
    const int lane = t & 63;
    const int m = lane & 15;
    const int quad = lane >> 4;
    const int row0 = blockIdx.x * 64;
    const int col0 = blockIdx.y * 64;
    const int r_st = t >> 2;
    const int seg  = (t & 3) * 8;
    f32x4 acc[4] = {{0.f,0.f,0.f,0.f},{0.f,0.f,0.f,0.f},{0.f,0.f,0.f,0.f},{0.f,0.f,0.f,0.f}};
    for (int k0 = 0; k0 < K; k0 += 32) {
        int gr = row0 + r_st;
        f16x8 av = {0,0,0,0,0,0,0,0};
        if (gr < nrows) av = *(const f16x8*)&A[(size_t)gr * K + k0 + seg];
        *(f16x8*)&As[r_st * LDA + seg] = av;
        f16x8 bv = *(const f16x8*)&Wt[(size_t)(col0 + r_st) * K + k0 + seg];
        *(f16x8*)&Bs[r_st * LDA + seg] = bv;
        __syncthreads();
        f16x8 af = *(const f16x8*)&As[(w * 16 + m) * LDA + quad * 8];
        #pragma unroll
        for (int g = 0; g < 4; ++g) {
            f16x8 bf = *(const f16x8*)&Bs[(g * 16 + m) * LDA + quad * 8];
            acc[g] = __builtin_amdgcn_mfma_f32_16x16x32_f16(af, bf, acc[g], 0, 0, 0);
        }
        __syncthreads();
    }
    #pragma unroll
    for (int g = 0; g < 4; ++g) {
        #pragma unroll
        for (int reg = 0; reg < 4; ++reg) {
            int gr = row0 + w * 16 + quad * 4 + reg;
            int gc = col0 + g * 16 + m;
            if (gr < nrows) O[(size_t)gr * CN + gc] = (f16)acc[g][reg];
        }
    }
    if constexpr (H > 0) {
        constexpr int D = CN / H;
        const int head = col0 / D;
        float ps[4] = {}, pd[4] = {};
        #pragma unroll
        for (int g = 0; g < 4; ++g) {
            int col = col0 + g * 16 + m;
            float a_s = asrc[col], a_d = adst[col];
            #pragma unroll
            for (int reg = 0; reg < 4; ++reg) {
                ps[reg] += acc[g][reg] * a_s;
                pd[reg] += acc[g][reg] * a_d;
            }
        }
        #pragma unroll
        for (int off = 1; off < 16; off <<= 1) {
            #pragma unroll
            for (int reg = 0; reg < 4; ++reg) {
                ps[reg] += __shfl_xor(ps[reg], off, 64);
                pd[reg] += __shfl_xor(pd[reg], off, 64);
            }
        }
        if (m == 0) {
            #pragma unroll
            for (int reg = 0; reg < 4; ++reg) {
                int gr = row0 + w * 16 + quad * 4 + reg;
                if (gr < nrows) {
                    atomicAdd(&als[gr * H + head], ps[reg]);
                    atomicAdd(&ald[gr * H + head], pd[reg]);
                }
            }
        }
    }
}

// ----- layer-1 per-head GEMM with fused bias+ELU -----
__global__ __launch_bounds__(256) void k_gemm1h(const f16* __restrict__ A,
                                                const f16* __restrict__ Wt1,
                                                const float* __restrict__ bias,
                                                f16* __restrict__ O,
                                                int nrows)
{
    constexpr int LDA = 40;
    __shared__ f16 As[64 * LDA];
    __shared__ f16 Bs[64 * LDA];
    const int t = threadIdx.x;
    const int w = t >> 6;
    const int lane = t & 63;
    const int m = lane & 15;
    const int quad = lane >> 4;
    const int row0 = blockIdx.x * 64;
    const int head = blockIdx.y;
    const int r_st = t >> 2;
    const int seg  = (t & 3) * 8;
    f32x4 acc[4] = {{0.f,0.f,0.f,0.f},{0.f,0.f,0.f,0.f},{0.f,0.f,0.f,0.f},{0.f,0.f,0.f,0.f}};
    for (int k0 = 0; k0 < 64; k0 += 32) {
        int gr = row0 + r_st;
        f16x8 av = {0,0,0,0,0,0,0,0};
        if (gr < nrows) av = *(const f16x8*)&A[(size_t)gr * 256 + head * 64 + k0 + seg];
        *(f16x8*)&As[r_st * LDA + seg] = av;
        f16x8 bv = *(const f16x8*)&Wt1[(size_t)head * 4096 + (size_t)r_st * 64 + k0 + seg];
        *(f16x8*)&Bs[r_st * LDA + seg] = bv;
        __syncthreads();
        f16x8 af = *(const f16x8*)&As[(w * 16 + m) * LDA + quad * 8];
        #pragma unroll
        for (int g = 0; g < 4; ++g) {
            f16x8 bf = *(const f16x8*)&Bs[(g * 16 + m) * LDA + quad * 8];
            acc[g] = __builtin_amdgcn_mfma_f32_16x16x32_f16(af, bf, acc[g], 0, 0, 0);
        }
        __syncthreads();
    }
    #pragma unroll
    for (int g = 0; g < 4; ++g) {
        #pragma unroll
        for (int reg = 0; reg < 4; ++reg) {
            int gr = row0 + w * 16 + quad * 4 + reg;
            int col = head * 64 + g * 16 + m;
            if (gr < nrows) {
                float v = acc[g][reg] + bias[col];
                v = v > 0.f ? v : (__expf(v) - 1.f);
                O[(size_t)gr * 256 + col] = (f16)v;
            }
        }
    }
}

// -------- per-edge exp weights --------
template<int H>
__global__ __launch_bounds__(256) void k_ew(const int* __restrict__ csr,
                                            const int* __restrict__ dstarr,
                                            const float* __restrict__ als,
                                            const float* __restrict__ ald,
                                            float* __restrict__ earr)
{
    int i = blockIdx.x * 256 + threadIdx.x;
    if (i >= ETOT) return;
    int s = csr[i], d = dstarr[i];
    #pragma unroll
    for (int hh = 0; hh < H; ++hh) {
        float l = als[s * H + hh] + ald[d * H + hh];
        l = l > 0.f ? l : 0.2f * l;
        earr[(size_t)i * H + hh] = __expf(fminf(l, 80.f));
    }
}

// ------- layer-1 aggregate over xc: 2 parities, f16x2 loads, 4-edge unroll -------
__global__ __launch_bounds__(256) void k_aggx(const int* __restrict__ rowptr,
                                              const int* __restrict__ csr,
                                              const float* __restrict__ earr, // [i][4]
                                              const f16* __restrict__ xc,
                                              f16* __restrict__ xagg)
{
    int gid = blockIdx.x * 256 + threadIdx.x;
    int n = gid >> 6, lane = gid & 63;
    if (n >= NN) return;
    int p  = lane >> 5;
    int cb = (lane & 31) * 2;
    int r0 = rowptr[n], r1 = rowptr[n + 1];
    float a0[2] = {}, a1[2] = {}, a2[2] = {}, a3[2] = {};
    float d0 = 0.f, d1 = 0.f, d2 = 0.f, d3 = 0.f;
    int i = r0;
    for (; i + 4 <= r1; i += 4) {
        int i0 = i + p, i1 = i + 2 + p;
        int s0 = csr[i0], s1 = csr[i1];
        float4 e0 = *(const float4*)&earr[(size_t)i0 * 4];
        float4 e1 = *(const float4*)&earr[(size_t)i1 * 4];
        f16x2 x0 = *(const f16x2*)&xc[(size_t)s0 * 64 + cb];
        f16x2 x1 = *(const f16x2*)&xc[(size_t)s1 * 64 + cb];
        #pragma unroll
        for (int j = 0; j < 2; ++j) {
            float v0 = (float)x0[j], v1 = (float)x1[j];
            a0[j] += e0.x * v0 + e1.x * v1;
            a1[j] += e0.y * v0 + e1.y * v1;
            a2[j] += e0.z * v0 + e1.z * v1;
            a3[j] += e0.w * v0 + e1.w * v1;
        }
        d0 += e0.x + e1.x; d1 += e0.y + e1.y;
        d2 += e0.z + e1.z; d3 += e0.w + e1.w;
    }
    for (; i < r1; i += 2) {
        int ii = i + p;
        bool v = ii < r1;
        int s0 = csr[v ? ii : r0];
        float4 e0 = *(const float4*)&earr[(size_t)(v ? ii : r0) * 4];
        if (!v) { e0.x = 0.f; e0.y = 0.f; e0.z = 0.f; e0.w = 0.f; }
        f16x2 x0 = *(const f16x2*)&xc[(size_t)s0 * 64 + cb];
        #pragma unroll
        for (int j = 0; j < 2; ++j) {
            float v0 = (float)x0[j];
            a0[j] += e0.x * v0; a1[j] += e0.y * v0;
            a2[j] += e0.z * v0; a3[j] += e0.w * v0;
        }
        d0 += e0.x; d1 += e0.y; d2 += e0.z; d3 += e0.w;
    }
    #pragma unroll
    for (int j = 0; j < 2; ++j) {
        a0[j] += __shfl_xor(a0[j], 32, 64);
        a1[j] += __shfl_xor(a1[j], 32, 64);
        a2[j] += __shfl_xor(a2[j], 32, 64);
        a3[j] += __shfl_xor(a3[j], 32, 64);
    }
    d0 += __shfl_xor(d0, 32, 64);
    d1 += __shfl_xor(d1, 32, 64);
    d2 += __shfl_xor(d2, 32, 64);
    d3 += __shfl_xor(d3, 32, 64);
    if (p == 0) {
        float i0 = 1.f / d0, i1 = 1.f / d1, i2 = 1.f / d2, i3 = 1.f / d3;
        size_t base = (size_t)n * 256 + cb;
        f16x2 o0 = {(f16)(a0[0] * i0), (f16)(a0[1] * i0)};
        f16x2 o1 = {(f16)(a1[0] * i1), (f16)(a1[1] * i1)};
        f16x2 o2 = {(f16)(a2[0] * i2), (f16)(a2[1] * i2)};
        f16x2 o3 = {(f16)(a3[0] * i3), (f16)(a3[1] * i3)};
        *(f16x2*)&xagg[base]       = o0;
        *(f16x2*)&xagg[base + 64]  = o1;
        *(f16x2*)&xagg[base + 128] = o2;
        *(f16x2*)&xagg[base + 192] = o3;
    }
}

// ------- layer-2 aggregate: 32 lanes/row (f16x8), 2 edge-parities, 4x unroll -------
__global__ __launch_bounds__(256) void k_agg2f(const int* __restrict__ rowptr,
                                               const int* __restrict__ csr,
                                               const float* __restrict__ earr, // [i][2]
                                               const f16* __restrict__ h,
                                               const float* __restrict__ bias,
                                               f16* __restrict__ z)
{
    int gid = blockIdx.x * 256 + threadIdx.x;
    int n = gid >> 6, lane = gid & 63;
    if (n >= NN) return;
    int p  = lane >> 5;
    int cb = (lane & 31) * 8;
    int head = cb >> 7;
    int r0 = rowptr[n], r1 = rowptr[n + 1];
    float a[8] = {};
    float den = 0.f;
    int i = r0;
    for (; i + 8 <= r1; i += 8) {
        int i0 = i + p, i1 = i + 2 + p, i2 = i + 4 + p, i3 = i + 6 + p;
        int s0 = csr[i0], s1 = csr[i1], s2 = csr[i2], s3 = csr[i3];
        float e0 = earr[(size_t)i0 * 2 + head];
        float e1 = earr[(size_t)i1 * 2 + head];
        float e2 = earr[(size_t)i2 * 2 + head];
        float e3 = earr[(size_t)i3 * 2 + head];
        f16x8 h0 = *(const f16x8*)&h[(size_t)s0 * 256 + cb];
        f16x8 h1 = *(const f16x8*)&h[(size_t)s1 * 256 + cb];
        f16x8 h2 = *(const f16x8*)&h[(size_t)s2 * 256 + cb];
        f16x8 h3 = *(const f16x8*)&h[(size_t)s3 * 256 + cb];
        #pragma unroll
        for (int j = 0; j < 8; ++j)
            a[j] += e0 * (float)h0[j] + e1 * (float)h1[j]
                  + e2 * (float)h2[j] + e3 * (float)h3[j];
        den += e0 + e1 + e2 + e3;
    }
    for (; i < r1; i += 2) {
        int ii = i + p;
        bool v = ii < r1;
        int s0 = csr[v ? ii : r0];
        float e0 = v ? earr[(size_t)ii * 2 + head] : 0.f;
        f16x8 h0 = *(const f16x8*)&h[(size_t)s0 * 256 + cb];
        #pragma unroll
        for (int j = 0; j < 8; ++j) a[j] += e0 * (float)h0[j];
        den += e0;
    }
    #pragma unroll
    for (int j = 0; j < 8; ++j) a[j] += __shfl_xor(a[j], 32, 64);
    den += __shfl_xor(den, 32, 64);
    if (p == 0) {
        float inv = 1.f / den;
        f16x8 o;
        #pragma unroll
        for (int j = 0; j < 8; ++j) {
            float v = a[j] * inv + bias[cb + j];
            v = v > 0.f ? v : (__expf(v) - 1.f);
            o[j] = (f16)v;
        }
        *(f16x8*)&z[(size_t)n * 256 + cb] = o;
    }
}

// ------- layer-3 aggregate: 16 lanes/row (f16x8), 4 edge-parities, 2x unroll -------
__global__ __launch_bounds__(256) void k_agg3(const int* __restrict__ rowptr,
                                              const int* __restrict__ csr,
                                              const float* __restrict__ earr, // [i]
                                              const f16* __restrict__ h,
                                              const float* __restrict__ bias,
                                              f16* __restrict__ z)
{
    int gid = blockIdx.x * 256 + threadIdx.x;
    int n = gid >> 6, lane = gid & 63;
    if (n >= NN) return;
    int p  = lane >> 4;
    int cb = (lane & 15) * 8;
    int r0 = rowptr[n], r1 = rowptr[n + 1];
    float a[8] = {};
    float den = 0.f;
    int i = r0;
    for (; i + 8 <= r1; i += 8) {
        int i0 = i + p, i1 = i + 4 + p;
        int s0 = csr[i0], s1 = csr[i1];
        float e0 = earr[i0], e1 = earr[i1];
        f16x8 h0 = *(const f16x8*)&h[(size_t)s0 * 128 + cb];
        f16x8 h1 = *(const f16x8*)&h[(size_t)s1 * 128 + cb];
        #pragma unroll
        for (int j = 0; j < 8; ++j)
            a[j] += e0 * (float)h0[j] + e1 * (float)h1[j];
        den += e0 + e1;
    }
    for (; i < r1; i += 4) {
        int ii = i + p;
        bool v = ii < r1;
        int s0 = csr[v ? ii : r0];
        float e0 = v ? earr[ii] : 0.f;
        f16x8 h0 = *(const f16x8*)&h[(size_t)s0 * 128 + cb];
        #pragma unroll
        for (int j = 0; j < 8; ++j) a[j] += e0 * (float)h0[j];
        den += e0;
    }
    #pragma unroll
    for (int j = 0; j < 8; ++j) {
        a[j] += __shfl_xor(a[j], 16, 64);
        a[j] += __shfl_xor(a[j], 32, 64);
    }
    den += __shfl_xor(den, 16, 64);
    den += __shfl_xor(den, 32, 64);
    if (lane < 16) {
        float inv = 1.f / den;
        f16x8 o;
        #pragma unroll
        for (int j = 0; j < 8; ++j)
            o[j] = (f16)(a[j] * inv + bias[cb + j]);
        *(f16x8*)&z[(size_t)n * 128 + cb] = o;
    }
}

// ---------- MFMA decoder: 64 edges/block, ef[64][256]f16 @ Wtl[64][256]^T ----------
#define DLDA 264
__global__ __launch_bounds__(256) void k_decm(const f16* __restrict__ z3,
                                              const int* __restrict__ eli,
                                              const int* __restrict__ ntypes,
                                              const f16* __restrict__ Wtl,  // [64][256]
                                              const float* __restrict__ bl1,
                                              const float* __restrict__ Wl2,
                                              const float* __restrict__ bl2,
                                              const float* __restrict__ tb,
                                              float* __restrict__ out)
{
    __shared__ f16 As[64 * DLDA];
    __shared__ int sls[64], sld[64];
    const int t = threadIdx.x;
    const int e0 = blockIdx.x * 64;
    if (t < 64) {
        int e = e0 + t;
        sls[t] = (e < ELN) ? eli[e] : 0;
        sld[t] = (e < ELN) ? eli[ELN + e] : 0;
    }
    __syncthreads();
    {
        int r = t & 63;
        int seg = t >> 6;
        int base = seg * 64;
        int node = (base < 128) ? sls[r] : sld[r];
        int zoff = base & 127;
        #pragma unroll
        for (int j = 0; j < 8; ++j) {
            f16x8 v = *(const f16x8*)&z3[(size_t)node * 128 + zoff + j * 8];
            *(f16x8*)&As[r * DLDA + base + j * 8] = v;
        }
    }
    __syncthreads();
    const int w = t >> 6;
    const int lane = t & 63;
    const int m = lane & 15;
    const int quad = lane >> 4;
    f32x4 acc[4] = {{0.f,0.f,0.f,0.f},{0.f,0.f,0.f,0.f},{0.f,0.f,0.f,0.f},{0.f,0.f,0.f,0.f}};
    for (int k0 = 0; k0 < 256; k0 += 32) {
        f16x8 af = *(const f16x8*)&As[(w * 16 + m) * DLDA + k0 + quad * 8];
        #pragma unroll
        for (int g = 0; g < 4; ++g) {
            f16x8 bf = *(const f16x8*)&Wtl[(size_t)(g * 16 + m) * 256 + k0 + quad * 8];
            acc[g] = __builtin_amdgcn_mfma_f32_16x16x32_f16(af, bf, acc[g], 0, 0, 0);
        }
    }
    float s[4] = {0.f, 0.f, 0.f, 0.f};
    #pragma unroll
    for (int g = 0; g < 4; ++g) {
        int col = g * 16 + m;
        float b = bl1[col], wv = Wl2[col];
        #pragma unroll
        for (int reg = 0; reg < 4; ++reg) {
            float hv = fmaxf(acc[g][reg] + b, 0.f);
            s[reg] += hv * wv;
        }
    }
    #pragma unroll
    for (int off = 1; off < 16; off <<= 1) {
        #pragma unroll
        for (int reg = 0; reg < 4; ++reg) s[reg] += __shfl_xor(s[reg], off, 64);
    }
    if (m == 0) {
        float b2v = bl2[0];
        #pragma unroll
        for (int reg = 0; reg < 4; ++reg) {
            int r = w * 16 + quad * 4 + reg;
            int e = e0 + r;
            if (e < ELN) {
                out[e] = s[reg] + b2v +
                         tb[(size_t)ntypes[sls[r]] * NT + ntypes[sld[r]]];
            }
        }
    }
}

// ---------------- launch ----------------
extern "C" void kernel_launch(void* const* d_in, const int* in_sizes, int n_in,
                              void* d_out, int out_size, void* d_ws, size_t ws_size,
                              hipStream_t stream)
{
    const float* x   = (const float*)d_in[0];
    const int*   ei  = (const int*)d_in[1];
    const int*   eli = (const int*)d_in[2];
    const float* emb = (const float*)d_in[3];
    const float* W1  = (const float*)d_in[4];
    const float* as1 = (const float*)d_in[5];
    const float* ad1 = (const float*)d_in[6];
    const float* b1  = (const float*)d_in[7];
    const float* W2  = (const float*)d_in[8];
    const float* as2 = (const float*)d_in[9];
    const float* ad2 = (const float*)d_in[10];
    const float* b2  = (const float*)d_in[11];
    const float* W3  = (const float*)d_in[12];
    const float* as3 = (const float*)d_in[13];
    const float* ad3 = (const float*)d_in[14];
    const float* b3  = (const float*)d_in[15];
    const float* Wl1 = (const float*)d_in[16];
    const float* bl1 = (const float*)d_in[17];
    const float* Wl2 = (const float*)d_in[18];
    const float* bl2 = (const float*)d_in[19];
    const float* tb  = (const float*)d_in[20];
    float* out = (float*)d_out;

    char* ws = (char*)d_ws;
    size_t off = 0;
    auto alloc = [&](size_t bytes) { size_t o = off; off = (off + bytes + 255) & ~(size_t)255; return o; };
    int*   ntypes = (int*)  (ws + alloc((size_t)NN * 4));
    f16*   xc16   = (f16*)  (ws + alloc((size_t)NN * 64 * 2));
    int*   counts = (int*)  (ws + alloc((size_t)NN * 4));
    int*   cursor = (int*)  (ws + alloc((size_t)NN * 4));
    int*   rowptr = (int*)  (ws + alloc((size_t)(NN + 1) * 4));
    int*   csr    = (int*)  (ws + alloc((size_t)ETOT * 4));
    int*   dstarr = (int*)  (ws + alloc((size_t)ETOT * 4));
    int*   bsums  = (int*)  (ws + alloc((size_t)(SCAN_B + 1) * 4));
    int*   boff   = (int*)  (ws + alloc((size_t)(SCAN_B + 1) * 4));
    // score buffers: [als1:4NN][ald1:4NN][als2:2NN][ald2:2NN][als3:NN][ald3:NN]
    float* scores = (float*)(ws + alloc((size_t)NN * 14 * 4));
    float* als1 = scores;
    float* ald1 = scores + (size_t)NN * 4;
    float* als2 = scores + (size_t)NN * 8;
    float* ald2 = scores + (size_t)NN * 10;
    float* als3 = scores + (size_t)NN * 12;
    float* ald3 = scores + (size_t)NN * 13;
    float* earr   = (float*)(ws + alloc((size_t)ETOT * 4 * 4));
    f16*   h16    = (f16*)  (ws + alloc((size_t)NN * 256 * 2));   // also xagg
    f16*   z16    = (f16*)  (ws + alloc((size_t)NN * 256 * 2));
    f16*   Wt1    = (f16*)  (ws + alloc((size_t)4 * 64 * 64 * 2));
    f16*   Wt2    = (f16*)  (ws + alloc((size_t)256 * 256 * 2));
    f16*   Wt3    = (f16*)  (ws + alloc((size_t)128 * 256 * 2));
    f16*   Wtl    = (f16*)  (ws + alloc((size_t)64 * 256 * 2));
    float* a1ps   = (float*)(ws + alloc(256 * 4));
    float* a1pd   = (float*)(ws + alloc(256 * 4));

    // one upfront memset: counts + nothing else between; layer-2/3 score zeroing
    hipMemsetAsync(counts, 0, (size_t)NN * 4, stream);
    hipMemsetAsync(als2, 0, (size_t)NN * 6 * 4, stream);   // als2,ald2,als3,ald3

    const int gN   = (NN + 255) / 256;
    const int gE   = (ETOT + 255) / 256;
    const int RB   = (NN + 63) / 64;       // 782
    const int gW1  = (NN + 3) / 4;         // 1 wave/node

    k_pre1<<<1, 256, 0, stream>>>(W1, as1, ad1, a1ps, a1pd);
    k_prepatt<<<gW1, 256, 0, stream>>>(x, emb, a1ps, a1pd, xc16, ntypes, als1, ald1);
    k_cvtall<<<(131072 + 255) / 256, 256, 0, stream>>>(W1, W2, W3, Wl1, Wt1, Wt2, Wt3, Wtl);
    k_deg <<<gE, 256, 0, stream>>>(ei, counts);
    k_scan1<<<SCAN_B, 256, 0, stream>>>(counts, rowptr, bsums);
    k_scan2<<<1, 256, 0, stream>>>(bsums, boff);
    k_scan3<<<SCAN_B, 256, 0, stream>>>(rowptr, boff, counts, cursor, dstarr);
    k_fill<<<gE, 256, 0, stream>>>(ei, cursor, csr);

    // Layer 1 (linearity-swapped; scores from k_prepatt)
    k_ew<4><<<gE, 256, 0, stream>>>(csr, dstarr, als1, ald1, earr);
    k_aggx<<<gW1, 256, 0, stream>>>(rowptr, csr, earr, xc16, h16 /*xagg*/);
    k_gemm1h<<<dim3(RB, 4), 256, 0, stream>>>(h16 /*xagg*/, Wt1, b1, z16, NN);

    // Layer 2 (att fused into GEMM epilogue; buffers pre-zeroed upfront)
    k_gemmh<256, 256, 2><<<dim3(RB, 4), 256, 0, stream>>>(z16, Wt2, h16, NN, as2, ad2, als2, ald2);
    k_ew<2><<<gE, 256, 0, stream>>>(csr, dstarr, als2, ald2, earr);
    k_agg2f<<<gW1, 256, 0, stream>>>(rowptr, csr, earr, h16, b2, z16);

    // Layer 3 (att fused into GEMM epilogue; buffers pre-zeroed upfront)
    k_gemmh<256, 128, 1><<<dim3(RB, 2), 256, 0, stream>>>(z16, Wt3, h16, NN, as3, ad3, als3, ald3);
    k_ew<1><<<gE, 256, 0, stream>>>(csr, dstarr, als3, ald3, earr);
    k_agg3<<<gW1, 256, 0, stream>>>(rowptr, csr, earr, h16, b3, z16);

    // Decoder (MFMA)
    k_decm<<<(ELN + 63) / 64, 256, 0, stream>>>(z16, eli, ntypes, Wtl, bl1, Wl2, bl2, tb, out);
}